// Round 2
// baseline (706.032 us; speedup 1.0000x reference)
//
#include <hip/hip_runtime.h>
#include <hip/hip_bf16.h>

typedef __bf16 bf16_t;
typedef __attribute__((ext_vector_type(8))) __bf16 bf16x8;
typedef __attribute__((ext_vector_type(4))) __bf16 bf16x4;
typedef __attribute__((ext_vector_type(4))) float f32x4;

#define D_IN   2048
#define D_SAE  16384
#define NROWS  4096
#define NFEAT  4096     // INIT_FEATURES (first NFEAT features unmasked; rest exactly zero)
#define TOPK   1638
#define W_EPS  1e-8f
#define LN_EPS 1e-5f
#define TEMP_INV 10.0f

// ---------------- reductions ----------------
__device__ inline float blockSumF(float v, float* red) {
#pragma unroll
  for (int o = 32; o; o >>= 1) v += __shfl_xor(v, o, 64);
  __syncthreads();
  if ((threadIdx.x & 63) == 0) red[threadIdx.x >> 6] = v;
  __syncthreads();
  return red[0] + red[1] + red[2] + red[3];
}

__device__ inline int blockSumI(int v, int* red) {
#pragma unroll
  for (int o = 32; o; o >>= 1) v += __shfl_xor(v, o, 64);
  __syncthreads();
  if ((threadIdx.x & 63) == 0) red[threadIdx.x >> 6] = v;
  __syncthreads();
  return red[0] + red[1] + red[2] + red[3];
}

// ---------------- W_enc column norms ----------------
__global__ __launch_bounds__(256) void col_norm_partial(const float* __restrict__ W,
                                                        float* __restrict__ part) {
  int col = blockIdx.x * 256 + threadIdx.x;   // 0..16383
  int rc = blockIdx.y;                        // 0..7
  const float* p = W + (size_t)rc * 256 * D_SAE + col;
  float s = 0.f;
#pragma unroll 8
  for (int r = 0; r < 256; ++r) {
    float v = p[(size_t)r * D_SAE];
    s += v * v;
  }
  part[(size_t)rc * D_SAE + col] = s;
}

__global__ __launch_bounds__(256) void col_norm_finalize(const float* __restrict__ part,
                                                         float* __restrict__ scale) {
  int col = blockIdx.x * 256 + threadIdx.x;
  float s = 0.f;
#pragma unroll
  for (int c = 0; c < 8; ++c) s += part[(size_t)c * D_SAE + col];
  scale[col] = 1.0f / (sqrtf(s) + W_EPS);
}

// ---------------- W_dec row norms (rows 0..NFEAT-1), one wave per row ----------------
__global__ __launch_bounds__(256) void row_norm_kernel(const float* __restrict__ W,
                                                       float* __restrict__ scale) {
  int gw = (blockIdx.x * 256 + threadIdx.x) >> 6;  // row
  int lane = threadIdx.x & 63;
  const float4* r4 = (const float4*)(W + (size_t)gw * D_IN);
  float s = 0.f;
#pragma unroll
  for (int i = 0; i < (D_IN / 4) / 64; ++i) {  // 8 iters
    float4 v = r4[lane + i * 64];
    s += v.x * v.x + v.y * v.y + v.z * v.z + v.w * v.w;
  }
#pragma unroll
  for (int o = 32; o; o >>= 1) s += __shfl_xor(s, o, 64);
  if (lane == 0) scale[gw] = 1.0f / (sqrtf(s) + W_EPS);
}

// ---------------- transpose + scale + cast to bf16 ----------------
// in: rows x C (row-major); take rows [0,Rout): out[c*Rout + r] = in[r][c]*scale
template <int SCALE_AXIS>
__global__ __launch_bounds__(256) void transpose_scale_cast(
    const float* __restrict__ in, const float* __restrict__ scale,
    bf16_t* __restrict__ out, int C, int Rout) {
  __shared__ float t[64][65];
  int c0 = blockIdx.x * 64;
  int r0 = blockIdx.y * 64;
  int tx = threadIdx.x & 63;
  int ty = threadIdx.x >> 6;
#pragma unroll
  for (int i = 0; i < 16; ++i) {
    int r = ty * 16 + i;
    float v = in[(size_t)(r0 + r) * C + (c0 + tx)];
    float sc = (SCALE_AXIS == 0) ? scale[c0 + tx] : scale[r0 + r];
    t[r][tx] = v * sc;
  }
  __syncthreads();
#pragma unroll
  for (int i = 0; i < 16; ++i) {
    int r = ty * 16 + i;  // output row within tile (= input col)
    out[(size_t)(c0 + r) * Rout + (r0 + tx)] = (bf16_t)t[tx][r];
  }
}

// ---------------- cast acts f32 -> bf16 ----------------
__global__ __launch_bounds__(256) void cast_bf16_kernel(const float* __restrict__ in,
                                                        bf16_t* __restrict__ out, int n4) {
  int i = blockIdx.x * 256 + threadIdx.x;
  if (i < n4) {
    float4 v = ((const float4*)in)[i];
    bf16x4 o;
    o[0] = (bf16_t)v.x; o[1] = (bf16_t)v.y; o[2] = (bf16_t)v.z; o[3] = (bf16_t)v.w;
    *(bf16x4*)(out + (size_t)i * 4) = o;
  }
}

// ---------------- unified MFMA GEMM:  C = A * B(+norm) + bias ----------------
// AMODE 0: A bf16 MxK row-major, staged via global_load_lds
// AMODE 1: A f32  MxK row-major, reg-staged + cast
// BMODE 0: B given as BT bf16 NxK row-major (pre-normalized), global_load_lds
// BMODE 1: B f32 KxN row-major, scaled by bscale[col] (per output column)
// BMODE 2: B f32 KxN row-major, scaled by bscale[k]   (per k row)
__device__ inline void gload_lds16(const bf16_t* g, bf16_t* l) {
  __builtin_amdgcn_global_load_lds((__attribute__((address_space(1))) void*)g,
                                   (__attribute__((address_space(3))) void*)l,
                                   16, 0, 0);
}

template <int AMODE, int BMODE>
__global__ __launch_bounds__(256, 2) void gemm_tile(
    const void* __restrict__ Ap, const void* __restrict__ Bp,
    const float* __restrict__ bscale, const float* __restrict__ bias,
    float* __restrict__ C, int N, int K, int lda, int ldb) {
  __shared__ __align__(16) bf16_t As[128 * 32];
  __shared__ __align__(16) bf16_t Bs[128 * 32];
  const int tid = threadIdx.x;
  const int lane = tid & 63;
  const int wid = tid >> 6;
  const int wm = wid >> 1, wn = wid & 1;
  const long brow = (long)blockIdx.y * 128;
  const long bcol = (long)blockIdx.x * 128;

  f32x4 acc[4][4] = {};

  const bf16_t* ag = nullptr; bf16_t* al = nullptr;
  const float* af32 = nullptr;
  if (AMODE == 0) {
    ag = (const bf16_t*)Ap + (size_t)(brow + wid * 32 + (lane >> 2)) * lda + (lane & 3) * 8;
    al = &As[(wid * 32) * 32];
  } else {
    af32 = (const float*)Ap;
  }
  const bf16_t* bg = nullptr; bf16_t* bl = nullptr;
  const float* bf32 = nullptr;
  if (BMODE == 0) {
    bg = (const bf16_t*)Bp + (size_t)(bcol + wid * 32 + (lane >> 2)) * ldb + (lane & 3) * 8;
    bl = &Bs[(wid * 32) * 32];
  } else {
    bf32 = (const float*)Bp;
  }

  const int fr = lane & 15;
  const int kc = (lane >> 4) * 8;
  const int aoff0 = (wm * 64 + fr) * 32 + kc;
  const int boff0 = (wn * 64 + fr) * 32 + kc;

  for (int kt = 0; kt < K; kt += 32) {
    if (AMODE == 0) {
      gload_lds16(ag + kt, al);
      gload_lds16(ag + kt + (size_t)16 * lda, al + 16 * 32);
    } else {
#pragma unroll
      for (int i = 0; i < 4; ++i) {
        int flat = tid + i * 256;          // 0..1023 float4s of the 128x32 tile
        int r = flat >> 3;                 // 0..127
        int k4 = flat & 7;                 // 0..7 -> k = k4*4..+3
        float4 v = *(const float4*)&af32[(size_t)(brow + r) * lda + kt + k4 * 4];
        bf16x4 o;
        o[0] = (bf16_t)v.x; o[1] = (bf16_t)v.y; o[2] = (bf16_t)v.z; o[3] = (bf16_t)v.w;
        *(bf16x4*)&As[r * 32 + k4 * 4] = o;
      }
    }
    if (BMODE == 0) {
      gload_lds16(bg + kt, bl);
      gload_lds16(bg + kt + (size_t)16 * ldb, bl + 16 * 32);
    } else {
#pragma unroll
      for (int i = 0; i < 4; ++i) {
        int flat = tid + i * 256;
        int k = flat >> 5;                 // 0..31
        int c4 = flat & 31;                // cols c4*4..+3
        float4 v = *(const float4*)&bf32[(size_t)(kt + k) * ldb + bcol + c4 * 4];
        float4 sc;
        if (BMODE == 1) {
          sc = *(const float4*)&bscale[bcol + c4 * 4];
        } else {
          float s = bscale[kt + k];
          sc.x = s; sc.y = s; sc.z = s; sc.w = s;
        }
        Bs[(c4 * 4 + 0) * 32 + k] = (bf16_t)(v.x * sc.x);
        Bs[(c4 * 4 + 1) * 32 + k] = (bf16_t)(v.y * sc.y);
        Bs[(c4 * 4 + 2) * 32 + k] = (bf16_t)(v.z * sc.z);
        Bs[(c4 * 4 + 3) * 32 + k] = (bf16_t)(v.w * sc.w);
      }
    }
    __syncthreads();
    bf16x8 afr[4], bfr[4];
#pragma unroll
    for (int m = 0; m < 4; ++m) afr[m] = *(const bf16x8*)&As[aoff0 + m * 16 * 32];
#pragma unroll
    for (int n = 0; n < 4; ++n) bfr[n] = *(const bf16x8*)&Bs[boff0 + n * 16 * 32];
#pragma unroll
    for (int m = 0; m < 4; ++m)
#pragma unroll
      for (int n = 0; n < 4; ++n)
        acc[m][n] = __builtin_amdgcn_mfma_f32_16x16x32_bf16(afr[m], bfr[n], acc[m][n], 0, 0, 0);
    __syncthreads();
  }

  float bval[4];
#pragma unroll
  for (int n = 0; n < 4; ++n) bval[n] = bias[bcol + wn * 64 + n * 16 + fr];
#pragma unroll
  for (int m = 0; m < 4; ++m) {
#pragma unroll
    for (int r = 0; r < 4; ++r) {
      size_t row = brow + wm * 64 + m * 16 + (lane >> 4) * 4 + r;
      float* cp = C + row * (size_t)N + bcol + wn * 64 + fr;
#pragma unroll
      for (int n = 0; n < 4; ++n) cp[n * 16] = acc[m][n][r] + bval[n];
    }
  }
}

// ---------------- per-row: LN -> affine -> LN -> exact topK thr -> encoded(bf16, first NFEAT) ----------------
__global__ __launch_bounds__(256) void row_process(
    const float* __restrict__ pre, const float* __restrict__ ln_w,
    const float* __restrict__ ln_b, const float* __restrict__ fmask,
    bf16_t* __restrict__ enc_base) {
  __shared__ float redf[4];
  __shared__ int redi[4];
  const int tid = threadIdx.x;
  const size_t row = blockIdx.x;
  const float4* xr = (const float4*)(pre + row * D_SAE);

  float4 x[16];
  float s = 0.f, s2 = 0.f;
#pragma unroll
  for (int j = 0; j < 16; ++j) {
    float4 v = xr[tid + j * 256];
    x[j] = v;
    s += v.x + v.y + v.z + v.w;
    s2 += v.x * v.x + v.y * v.y + v.z * v.z + v.w * v.w;
  }
  float S1 = blockSumF(s, redf);
  float S2 = blockSumF(s2, redf);
  float mu = S1 * (1.0f / D_SAE);
  float var = S2 * (1.0f / D_SAE) - mu * mu;
  float inv = rsqrtf(var + LN_EPS);

  const float4* wr = (const float4*)ln_w;
  const float4* br = (const float4*)ln_b;
  s = 0.f; s2 = 0.f;
#pragma unroll
  for (int j = 0; j < 16; ++j) {
    float4 w = wr[tid + j * 256];
    float4 b = br[tid + j * 256];
    float4 h;
    h.x = (x[j].x - mu) * inv * w.x + b.x;
    h.y = (x[j].y - mu) * inv * w.y + b.y;
    h.z = (x[j].z - mu) * inv * w.z + b.z;
    h.w = (x[j].w - mu) * inv * w.w + b.w;
    x[j] = h;
    s += h.x + h.y + h.z + h.w;
    s2 += h.x * h.x + h.y * h.y + h.z * h.z + h.w * h.w;
  }
  float T1 = blockSumF(s, redf);
  float T2 = blockSumF(s2, redf);
  float mu2 = T1 * (1.0f / D_SAE);
  float inv2 = rsqrtf(T2 * (1.0f / D_SAE) - mu2 * mu2 + LN_EPS);
#pragma unroll
  for (int j = 0; j < 16; ++j) {
    x[j].x = (x[j].x - mu2) * inv2;
    x[j].y = (x[j].y - mu2) * inv2;
    x[j].z = (x[j].z - mu2) * inv2;
    x[j].w = (x[j].w - mu2) * inv2;
  }

  // exact K-th largest via 32-bit binary search on order-preserving key
  unsigned ans = 0u;
  for (int bit = 31; bit >= 0; --bit) {
    unsigned u = ans | (1u << bit);
    unsigned bb = (u & 0x80000000u) ? (u ^ 0x80000000u) : ~u;
    float tc = __uint_as_float(bb);
    int c = 0;
#pragma unroll
    for (int j = 0; j < 16; ++j) {
      c += (x[j].x >= tc) ? 1 : 0;
      c += (x[j].y >= tc) ? 1 : 0;
      c += (x[j].z >= tc) ? 1 : 0;
      c += (x[j].w >= tc) ? 1 : 0;
    }
    c = blockSumI(c, redi);
    if (c >= TOPK) ans = u;
  }
  unsigned tb = (ans & 0x80000000u) ? (ans ^ 0x80000000u) : ~ans;
  float thr = __uint_as_float(tb);

  // encoded for first NFEAT features only (rest exactly zero via feature_mask)
  const float4* mr = (const float4*)fmask;
#pragma unroll
  for (int j = 0; j < NFEAT / 1024; ++j) {  // 4 groups cover cols 0..4095
    float4 m = mr[tid + j * 256];
    float4 h = x[j];
    float4 e;
    e.x = h.x * m.x / (1.0f + __expf((thr - h.x) * TEMP_INV));
    e.y = h.y * m.y / (1.0f + __expf((thr - h.y) * TEMP_INV));
    e.z = h.z * m.z / (1.0f + __expf((thr - h.z) * TEMP_INV));
    e.w = h.w * m.w / (1.0f + __expf((thr - h.w) * TEMP_INV));
    bf16x4 o;
    o[0] = (bf16_t)e.x; o[1] = (bf16_t)e.y; o[2] = (bf16_t)e.z; o[3] = (bf16_t)e.w;
    *(bf16x4*)(enc_base + (size_t)row * NFEAT + (size_t)(tid + j * 256) * 4) = o;
  }
}

// ---------------- launch ----------------
extern "C" void kernel_launch(void* const* d_in, const int* in_sizes, int n_in,
                              void* d_out, int out_size, void* d_ws, size_t ws_size,
                              hipStream_t stream) {
  const float* acts  = (const float*)d_in[0];
  const float* W_enc = (const float*)d_in[1];
  const float* W_dec = (const float*)d_in[2];
  const float* b_enc = (const float*)d_in[3];
  const float* b_dec = (const float*)d_in[4];
  const float* ln_w  = (const float*)d_in[5];
  const float* ln_b  = (const float*)d_in[6];
  const float* fmask = (const float*)d_in[7];
  float* out = (float*)d_out;
  char* ws = (char*)d_ws;

  const size_t MB = 1u << 20;
  const size_t SMALL = MB;                              // scales + colpart
  const size_t SZ_WencT = (size_t)D_SAE * D_IN * 2;     // 64 MB
  const size_t SZ_WdecT = (size_t)D_IN * NFEAT * 2;     // 16 MB
  const size_t SZ_actsb = (size_t)NROWS * D_IN * 2;     // 16 MB
  const size_t SZ_enc   = (size_t)NROWS * NFEAT * 2;    // 32 MB
  const size_t ROWB_pre = (size_t)D_SAE * 4;            // 64 KB / row
  const size_t ROWB_enc = (size_t)NFEAT * 2;            // 8 KB / row

  float* scale_enc = (float*)(ws + 0);
  float* scale_dec = (float*)(ws + 64 * 1024);
  float* colpart   = (float*)(ws + 128 * 1024);

  // ---- plan selection from ws_size ----
  int plan;
  size_t CH;
  const size_t baseA = SMALL + SZ_WencT + SZ_WdecT + SZ_actsb + SZ_enc;  // 129 MB
  const size_t baseC = SMALL + SZ_WdecT + SZ_actsb + SZ_enc;             // 65 MB
  const size_t baseD = SMALL;
  if (ws_size >= baseA + 128 * ROWB_pre) {
    plan = 0;
    CH = (ws_size - baseA) / ROWB_pre;
  } else if (ws_size >= baseC + 128 * ROWB_pre) {
    plan = 1;
    CH = (ws_size - baseC) / ROWB_pre;
  } else if (ws_size >= baseD + 128 * (ROWB_pre + ROWB_enc)) {
    plan = 2;
    CH = (ws_size - baseD) / (ROWB_pre + ROWB_enc);
  } else {
    return;  // not enough workspace for any plan
  }
  CH = (CH / 128) * 128;
  if (CH > NROWS) CH = NROWS;

  // ---- ws layout ----
  size_t off = SMALL;
  bf16_t* WencT = nullptr; bf16_t* WdecT = nullptr; bf16_t* actsb = nullptr;
  bf16_t* enc = nullptr; bf16_t* encC = nullptr; float* pre = nullptr;
  if (plan == 0) { WencT = (bf16_t*)(ws + off); off += SZ_WencT; }
  if (plan <= 1) {
    WdecT = (bf16_t*)(ws + off); off += SZ_WdecT;
    actsb = (bf16_t*)(ws + off); off += SZ_actsb;
    enc   = (bf16_t*)(ws + off); off += SZ_enc;
  }
  pre = (float*)(ws + off); off += CH * ROWB_pre;
  if (plan == 2) { encC = (bf16_t*)(ws + off); off += CH * ROWB_enc; }

  // ---- normalization scales ----
  col_norm_partial<<<dim3(64, 8), 256, 0, stream>>>(W_enc, colpart);
  col_norm_finalize<<<64, 256, 0, stream>>>(colpart, scale_enc);
  row_norm_kernel<<<NFEAT / 4, 256, 0, stream>>>(W_dec, scale_dec);

  // ---- weight prep ----
  if (plan == 0)
    transpose_scale_cast<0><<<dim3(D_SAE / 64, D_IN / 64), 256, 0, stream>>>(
        W_enc, scale_enc, WencT, D_SAE, D_IN);
  if (plan <= 1) {
    transpose_scale_cast<1><<<dim3(D_IN / 64, NFEAT / 64), 256, 0, stream>>>(
        W_dec, scale_dec, WdecT, D_IN, NFEAT);
    cast_bf16_kernel<<<(NROWS * D_IN / 4 + 255) / 256, 256, 0, stream>>>(
        acts, actsb, NROWS * D_IN / 4);
  }

  // ---- chunked pipeline ----
  for (size_t r0 = 0; r0 < NROWS; r0 += CH) {
    size_t Mi = NROWS - r0 < CH ? NROWS - r0 : CH;
    if (plan == 0)
      gemm_tile<0, 0><<<dim3(D_SAE / 128, Mi / 128), 256, 0, stream>>>(
          actsb + r0 * D_IN, WencT, nullptr, b_enc, pre, D_SAE, D_IN, D_IN, D_IN);
    else if (plan == 1)
      gemm_tile<0, 1><<<dim3(D_SAE / 128, Mi / 128), 256, 0, stream>>>(
          actsb + r0 * D_IN, W_enc, scale_enc, b_enc, pre, D_SAE, D_IN, D_IN, D_SAE);
    else
      gemm_tile<1, 1><<<dim3(D_SAE / 128, Mi / 128), 256, 0, stream>>>(
          acts + r0 * D_IN, W_enc, scale_enc, b_enc, pre, D_SAE, D_IN, D_IN, D_SAE);

    bf16_t* encdst = (plan == 2) ? encC : enc + r0 * NFEAT;
    row_process<<<Mi, 256, 0, stream>>>(pre, ln_w, ln_b, fmask, encdst);

    if (plan == 2)
      gemm_tile<0, 2><<<dim3(D_IN / 128, Mi / 128), 256, 0, stream>>>(
          encC, W_dec, scale_dec, b_dec, out + r0 * D_IN, D_IN, NFEAT, NFEAT, D_IN);
  }
  if (plan != 2)
    gemm_tile<0, 0><<<dim3(D_IN / 128, NROWS / 128), 256, 0, stream>>>(
        enc, WdecT, nullptr, b_dec, out, D_IN, NFEAT, NFEAT, NFEAT);
}